// Round 9
// baseline (2379.830 us; speedup 1.0000x reference)
//
#include <hip/hip_runtime.h>
#include <math.h>

// Residual SF-DiVeQ (N=65536, D=64, C=4, K=1024) — bit-exact numpy-fp32 argmin.
// R9: same as R8 but the register pin is per-SCALAR (gfx950 inline asm can't
// tie multi-register float4 operands — "tied indirect register inputs").
// PIN4 = empty asm tying the 4 components of one float4 -> compiler cannot
// rematerialize the codeword loads inside the row loop (R7 VGPR=40 proved it
// was re-gathering 1KB/row). 2 rows/iter ILP; f32 min reduce + ballot/ffs
// argmin (exact numpy first-index ties via lane-ascending k + u64 merge).
// FMA floor: 1.72e10 FMA / 78.6 T-FMA/s = 219 us.

#define N_PTS 65536
#define DIM 64
#define NCB 4
#define KCB 1024
#define PARTS 4
#define KP (KCB / PARTS)        // 256 codewords per partition (4 waves x 64)
#define RB 512                  // row-blocks per partition
#define RPB (N_PTS / RB)        // 128 rows per dist block

typedef unsigned long long u64;

// ---------------- prep: cn[c][k] = numpy-pairwise ||c_k||^2, zero counts -----
__global__ __launch_bounds__(256) void prep_kernel(const float* __restrict__ cb,
    float* __restrict__ cnp, int* __restrict__ counts)
{
#pragma clang fp contract(off)
    int t = blockIdx.x * 256 + threadIdx.x;       // grid 16 -> 4096 = C*K
    const float* row = cb + (size_t)t * DIM;
    float pr[8];
#pragma unroll
    for (int j = 0; j < 8; ++j) { float v = row[j]; pr[j] = v * v; }
#pragma unroll
    for (int i = 8; i < DIM; i += 8)
#pragma unroll
        for (int j = 0; j < 8; ++j) { float v = row[i + j]; pr[j] += v * v; }
    cnp[t] = ((pr[0] + pr[1]) + (pr[2] + pr[3])) + ((pr[4] + pr[5]) + (pr[6] + pr[7]));
    counts[t] = 0;
}

// ---------------- uprr: rem = src - cb[ix] (fp32 single-rounded) + srr -------
__global__ __launch_bounds__(256) void uprr_kernel(
    const float* __restrict__ src, const float* __restrict__ cbc,
    const int* __restrict__ ixp, float* __restrict__ rem, float* __restrict__ srr)
{
#pragma clang fp contract(off)
    int lane = threadIdx.x & 63;
    int n = blockIdx.x * 4 + (threadIdx.x >> 6);   // grid 16384
    size_t e = (size_t)n * DIM + lane;
    float r = src[e];
    if (cbc) {
        int ix = ixp[n];                            // wave-uniform broadcast
        r = r - cbc[(size_t)ix * DIM + lane];       // single rounding
        rem[e] = r;
    }
    float sq = r * r;
    float pr = sq;
#pragma unroll
    for (int i = 1; i < 8; ++i) pr += __shfl(sq, (lane & 7) + 8 * i);
    pr += __shfl_xor(pr, 1);
    pr += __shfl_xor(pr, 2);
    pr += __shfl_xor(pr, 4);
    if (lane == 0) srr[n] = pr;
}

// ---------------- dist: lane = codeword, rows streamed wave-uniform ----------
#define PIN4(Q) asm volatile("" : "+v"(Q.x), "+v"(Q.y), "+v"(Q.z), "+v"(Q.w));

#define FMA4(ACC, RA, QA) \
    ACC = fmaf(RA.x, QA.x, ACC); ACC = fmaf(RA.y, QA.y, ACC); \
    ACC = fmaf(RA.z, QA.z, ACC); ACC = fmaf(RA.w, QA.w, ACC);

#define STEP(J, QJ) \
    ra = r0p[J]; FMA4(a0, ra, QJ); \
    rbv = r1p[J]; FMA4(a1, rbv, QJ);

__global__ __launch_bounds__(256, 4) void dist_kernel(
    const float* __restrict__ src, const float* __restrict__ cbc,
    const float* __restrict__ cnc, const float* __restrict__ srr,
    u64* __restrict__ pm)
{
#pragma clang fp contract(off)
    int lane = threadIdx.x & 63;
    int wv = threadIdx.x >> 6;
    int part = blockIdx.x & 3;
    int rb = blockIdx.x >> 2;
    int kw = part * KP + wv * 64;                  // wave's k base
    int k = kw + lane;                             // this lane's codeword

    const float4* cw = (const float4*)(cbc + (size_t)k * DIM);
    float4 q0 = cw[0],  q1 = cw[1],  q2 = cw[2],  q3 = cw[3];
    float4 q4 = cw[4],  q5 = cw[5],  q6 = cw[6],  q7 = cw[7];
    float4 q8 = cw[8],  q9 = cw[9],  q10 = cw[10], q11 = cw[11];
    float4 q12 = cw[12], q13 = cw[13], q14 = cw[14], q15 = cw[15];
    float cn = cnc[k];
    // pin each scalar component: opaque asm results -> no remat inside loop
    PIN4(q0)  PIN4(q1)  PIN4(q2)  PIN4(q3)
    PIN4(q4)  PIN4(q5)  PIN4(q6)  PIN4(q7)
    PIN4(q8)  PIN4(q9)  PIN4(q10) PIN4(q11)
    PIN4(q12) PIN4(q13) PIN4(q14) PIN4(q15)
    asm volatile("" : "+v"(cn));

    int s = part * 4 + wv;                          // partial slot (k ascending)

    for (int r = 0; r < RPB; r += 2) {
        int n0 = rb * RPB + r;                      // uniform row ids
        const float4* r0p = (const float4*)(src + (size_t)n0 * DIM);
        const float4* r1p = (const float4*)(src + (size_t)(n0 + 1) * DIM);
        float sr0 = srr[n0], sr1 = srr[n0 + 1];
        float a0 = 0.0f, a1 = 0.0f;
        float4 ra, rbv;
        STEP(0, q0)   STEP(1, q1)   STEP(2, q2)   STEP(3, q3)
        STEP(4, q4)   STEP(5, q5)   STEP(6, q6)   STEP(7, q7)
        STEP(8, q8)   STEP(9, q9)   STEP(10, q10) STEP(11, q11)
        STEP(12, q12) STEP(13, q13) STEP(14, q14) STEP(15, q15)

        float t0 = 2.0f * a0;                       // exact
        float d0 = (sr0 - t0) + cn;                 // ref rounding order
        float t1 = 2.0f * a1;
        float d1 = (sr1 - t1) + cn;

        // wave-min of each dd (f32; all positive), two chains pipeline
        float m0 = d0, m1 = d1;
#pragma unroll
        for (int off = 1; off < 64; off <<= 1) {
            float o0 = __shfl_xor(m0, off);
            float o1 = __shfl_xor(m1, off);
            m0 = fminf(m0, o0);
            m1 = fminf(m1, o1);
        }
        u64 b0 = __ballot(d0 == m0);                // lowest set lane = lowest k
        u64 b1 = __ballot(d1 == m1);
        int k0win = kw + (__ffsll((unsigned long long)b0) - 1);
        int k1win = kw + (__ffsll((unsigned long long)b1) - 1);
        u64 key0 = ((u64)__float_as_uint(m0) << 32) | (unsigned)k0win;
        u64 key1 = ((u64)__float_as_uint(m1) << 32) | (unsigned)k1win;
        if (lane == 0) pm[(size_t)s * N_PTS + n0] = key0;
        if (lane == 1) pm[(size_t)s * N_PTS + n0 + 1] = key1;
    }
}

// ---------------- merge 16 per-wave partials (u64 min = exact ties) ----------
__global__ __launch_bounds__(256) void merge_kernel(
    const u64* __restrict__ pm, int* __restrict__ idx)
{
    int n = blockIdx.x * 256 + threadIdx.x;        // grid 256
    u64 m = pm[n];
#pragma unroll
    for (int s = 1; s < 16; ++s) {
        u64 v = pm[(size_t)s * N_PTS + n];
        if (v < m) m = v;
    }
    idx[n] = (int)(unsigned)(m & 0xffffffffu);
}

// ---------------- epilogue: z_q (fp64; threshold ~2% of magnitude) -----------
__global__ __launch_bounds__(256) void zq_kernel(
    const float* __restrict__ z, const float* __restrict__ noise,
    const float* __restrict__ cbase, const int* __restrict__ idxA,
    float* __restrict__ out)
{
    int lane = threadIdx.x & 63;
    int n = blockIdx.x * 4 + (threadIdx.x >> 6);   // grid 16384
    size_t e = (size_t)n * DIM + lane;
    double zd = z[e];
    double rd = zd;
#pragma unroll
    for (int cc = 0; cc < NCB; ++cc) {
        int id = idxA[cc * N_PTS + n];
        rd -= (double)cbase[((size_t)cc * KCB + id) * DIM + lane];
    }
    double dir = -rd;                               // z_hard - z
    double rv = fma(1e-3, (double)noise[e], dir);
    double srv = rv * rv, sdir = dir * dir;
#pragma unroll
    for (int off = 32; off >= 1; off >>= 1) {
        srv  += __shfl_xor(srv, off);
        sdir += __shfl_xor(sdir, off);
    }
    double em = sqrt(sdir);
    double nn = sqrt(srv); nn = nn > 1e-12 ? nn : 1e-12;
    out[e] = (float)(zd + em * rv / nn);
}

// ---------------- histogram + idx output (as float32) ------------------------
__global__ __launch_bounds__(256) void hist_kernel(
    const int* __restrict__ idxA, float* __restrict__ out_idx, int* __restrict__ counts)
{
    int t = blockIdx.x * 256 + threadIdx.x;        // C*N, grid 1024
    int v = idxA[t];
    out_idx[t] = (float)v;
    atomicAdd(&counts[(t >> 16) * KCB + v], 1);
}

// ---------------- perplexity -------------------------------------------------
__global__ __launch_bounds__(1024) void perp_kernel(const int* __restrict__ counts,
                                                    float* __restrict__ out)
{
    __shared__ double red[16];
    int tid = threadIdx.x, lane = tid & 63, w = tid >> 6;
    for (int c = 0; c < NCB; ++c) {
        double p = (double)counts[c * KCB + tid] / (double)N_PTS;
        double v = p * log(p + 1e-10);
#pragma unroll
        for (int off = 32; off >= 1; off >>= 1) v += __shfl_xor(v, off);
        if (lane == 0) red[w] = v;
        __syncthreads();
        if (tid == 0) {
            double ssum = 0.0;
            for (int i = 0; i < 16; ++i) ssum += red[i];
            out[c] = (float)exp(-ssum);
        }
        __syncthreads();
    }
}

extern "C" void kernel_launch(void* const* d_in, const int* in_sizes, int n_in,
                              void* d_out, int out_size, void* d_ws, size_t ws_size,
                              hipStream_t stream)
{
    const float* z     = (const float*)d_in[0];
    const float* cbook = (const float*)d_in[1];   // [C,K,D]
    const float* noise = (const float*)d_in[2];
    float* out = (float*)d_out;
    char* ws = (char*)d_ws;

    // rem scratch = d_out's z_q region (16MB), overwritten by zq at the end.
    float* rem = out;

    // ws layout (~9.3 MB)
    u64*   pm     = (u64*)  (ws);                  // 16*N u64   8,388,608 B
    int*   idxA   = (int*)  (ws + 8388608);        // C*N i32    1,048,576
    float* cnp    = (float*)(ws + 9437184);        // C*K f32       16,384
    int*   counts = (int*)  (ws + 9453568);        // C*K i32       16,384
    float* srr    = (float*)(ws + 9469952);        // N f32        262,144

    prep_kernel<<<16, 256, 0, stream>>>(cbook, cnp, counts);

    for (int c = 0; c < NCB; ++c) {
        const float* cb_prev = (c == 0) ? nullptr : cbook + (size_t)(c - 1) * KCB * DIM;
        const int*   ix_prev = (c == 0) ? nullptr : idxA + (size_t)(c - 1) * N_PTS;
        const float* usrc    = (c <= 1) ? z : rem;     // uprr input
        const float* dsrc    = (c == 0) ? z : rem;     // dist input
        uprr_kernel<<<N_PTS / 4, 256, 0, stream>>>(usrc, cb_prev, ix_prev, rem, srr);
        dist_kernel<<<PARTS * RB, 256, 0, stream>>>(
            dsrc, cbook + (size_t)c * KCB * DIM, cnp + c * KCB, srr, pm);
        merge_kernel<<<N_PTS / 256, 256, 0, stream>>>(pm, idxA + (size_t)c * N_PTS);
    }

    zq_kernel<<<N_PTS / 4, 256, 0, stream>>>(z, noise, cbook, idxA, out);
    hist_kernel<<<NCB * N_PTS / 256, 256, 0, stream>>>(
        idxA, out + (size_t)N_PTS * DIM, counts);
    perp_kernel<<<1, 1024, 0, stream>>>(
        counts, out + (size_t)N_PTS * DIM + (size_t)NCB * N_PTS);
}

// Round 11
// 991.640 us; speedup vs baseline: 2.3999x; 2.3999x over previous
//
#include <hip/hip_runtime.h>
#include <math.h>

// Residual SF-DiVeQ (N=65536, D=64, C=4, K=1024) — bit-exact numpy-fp32 argmin.
// R11 = R10 with the B-fragment addressing bug fixed: second K-half must be
// bh[4]/bl[4] (+32 elements), not bh[2] (+16). A-side already used +32.
//  bulk: d2_fast via bf16 MFMA 2-way splits (hi+lo), |err| <= ~2.3e-5;
//  (min1,min2) margin certification at 8e-5; flagged rows (-3%) -> exact
//  numpy-fp32 rescan (R3-verified recipe). Frag maps (AMD blog/m89):
//  A[row=lane&15][k=(lane>>4)*8+j], B[k=(lane>>4)*8+j][col=lane&15],
//  D[row=(lane>>4)*4+reg][col=lane&15].

#define N_PTS 65536
#define DIM 64
#define NCB 4
#define KCB 1024
#define MARGIN 8e-5f

typedef unsigned long long u64;
typedef short  s16x8 __attribute__((ext_vector_type(8)));
typedef float  f32x4 __attribute__((ext_vector_type(4)));

__device__ __forceinline__ unsigned short bf16_rne(float x) {
    unsigned u = __float_as_uint(x);
    u += 0x7fffu + ((u >> 16) & 1u);
    return (unsigned short)(u >> 16);
}
__device__ __forceinline__ float bf16_val(unsigned short h) {
    return __uint_as_float(((unsigned)h) << 16);
}

// ---------------- prep: cn (numpy-pairwise fp32), cb splits, zero counters ---
__global__ __launch_bounds__(256) void prep_kernel(const float* __restrict__ cb,
    float* __restrict__ cnp, unsigned short* __restrict__ cbh,
    unsigned short* __restrict__ cbl, int* __restrict__ counts,
    int* __restrict__ flagcnt)
{
#pragma clang fp contract(off)
    int t = blockIdx.x * 256 + threadIdx.x;       // grid 16 -> 4096 = C*K
    const float* row = cb + (size_t)t * DIM;
    float pr[8];
#pragma unroll
    for (int j = 0; j < 8; ++j) { float v = row[j]; pr[j] = v * v; }
#pragma unroll
    for (int i = 8; i < DIM; i += 8)
#pragma unroll
        for (int j = 0; j < 8; ++j) { float v = row[i + j]; pr[j] += v * v; }
    cnp[t] = ((pr[0] + pr[1]) + (pr[2] + pr[3])) + ((pr[4] + pr[5]) + (pr[6] + pr[7]));
    counts[t] = 0;
#pragma unroll
    for (int d = 0; d < DIM; ++d) {
        float x = row[d];
        unsigned short h = bf16_rne(x);
        unsigned short l = bf16_rne(x - bf16_val(h));
        cbh[(size_t)t * DIM + d] = h;
        cbl[(size_t)t * DIM + d] = l;
    }
    if (t < NCB) flagcnt[t] = 0;
}

// ---------------- uprr: rem update (fp32 single-rounded) + splits + srr ------
__global__ __launch_bounds__(256) void uprr_kernel(
    const float* __restrict__ src, const float* __restrict__ cbc,
    const int* __restrict__ ixp, float* __restrict__ rem,
    unsigned short* __restrict__ remh, unsigned short* __restrict__ reml,
    float* __restrict__ srr)
{
#pragma clang fp contract(off)
    int lane = threadIdx.x & 63;
    int n = blockIdx.x * 4 + (threadIdx.x >> 6);   // grid 16384
    size_t e = (size_t)n * DIM + lane;
    float r = src[e];
    if (cbc) {
        int ix = ixp[n];                            // wave-uniform broadcast
        r = r - cbc[(size_t)ix * DIM + lane];       // single rounding
    }
    rem[e] = r;
    unsigned short h = bf16_rne(r);
    unsigned short l = bf16_rne(r - bf16_val(h));
    remh[e] = h; reml[e] = l;
    // exact numpy pairwise srr (R7-verified shfl recipe)
    float sq = r * r;
    float pr = sq;
#pragma unroll
    for (int i = 1; i < 8; ++i) pr += __shfl(sq, (lane & 7) + 8 * i);
    pr += __shfl_xor(pr, 1);
    pr += __shfl_xor(pr, 2);
    pr += __shfl_xor(pr, 4);
    if (lane == 0) srr[n] = pr;
}

// ---------------- dist: MFMA bulk, (min1,min2) margin certification ----------
// block 256 = 4 waves; wave owns 32 rows (2 row-tiles of 16), scans all K.
__global__ __launch_bounds__(256, 4) void dist_kernel(
    const unsigned short* __restrict__ remh, const unsigned short* __restrict__ reml,
    const unsigned short* __restrict__ cbh, const unsigned short* __restrict__ cbl,
    const float* __restrict__ cnp, const float* __restrict__ srr,
    int* __restrict__ idxc, int* __restrict__ flagcnt_c, int* __restrict__ flaglist)
{
    int lane = threadIdx.x & 63;
    int wv = threadIdx.x >> 6;
    int g = lane >> 4;                              // frag group 0..3
    int lc = lane & 15;
    int n0 = blockIdx.x * 128 + wv * 32;            // wave's 32 rows

    // A fragments (held for the whole kernel): rows lane&15 (+16 for tile 1)
    int ar0 = n0 + lc, ar1 = ar0 + 16;
    s16x8 Ah00 = *(const s16x8*)(remh + (size_t)ar0 * DIM + g * 8);
    s16x8 Ah01 = *(const s16x8*)(remh + (size_t)ar0 * DIM + 32 + g * 8);
    s16x8 Al00 = *(const s16x8*)(reml + (size_t)ar0 * DIM + g * 8);
    s16x8 Al01 = *(const s16x8*)(reml + (size_t)ar0 * DIM + 32 + g * 8);
    s16x8 Ah10 = *(const s16x8*)(remh + (size_t)ar1 * DIM + g * 8);
    s16x8 Ah11 = *(const s16x8*)(remh + (size_t)ar1 * DIM + 32 + g * 8);
    s16x8 Al10 = *(const s16x8*)(reml + (size_t)ar1 * DIM + g * 8);
    s16x8 Al11 = *(const s16x8*)(reml + (size_t)ar1 * DIM + 32 + g * 8);

    // srr for D rows: row = g*4 + j (tile0), +16 (tile1)
    f32x4 srr0 = *(const f32x4*)(srr + n0 + g * 4);
    f32x4 srr1 = *(const f32x4*)(srr + n0 + 16 + g * 4);

    f32x4 m1_0 = (f32x4)3.4028235e38f, m2_0 = (f32x4)3.4028235e38f;
    f32x4 m1_1 = (f32x4)3.4028235e38f, m2_1 = (f32x4)3.4028235e38f;
    int ix0[4] = {0,0,0,0}, ix1[4] = {0,0,0,0};

    for (int t = 0; t < KCB / 16; ++t) {
        int col = t * 16 + lc;                      // this lane's codeword col
        const unsigned short* bhp = cbh + (size_t)col * DIM + g * 8;
        const unsigned short* blp = cbl + (size_t)col * DIM + g * 8;
        s16x8 Bh0 = *(const s16x8*)(bhp);           // d = g*8 .. g*8+7
        s16x8 Bh1 = *(const s16x8*)(bhp + 32);      // d = 32+g*8 .. 32+g*8+7  (FIXED)
        s16x8 Bl0 = *(const s16x8*)(blp);
        s16x8 Bl1 = *(const s16x8*)(blp + 32);      // (FIXED: was +16)
        float cnl = cnp[col];

        f32x4 za = (f32x4)0.0f, zb = (f32x4)0.0f;
        // row-tile 0
        f32x4 a = __builtin_amdgcn_mfma_f32_16x16x32_bf16(Ah00, Bh0, za, 0, 0, 0);
        a = __builtin_amdgcn_mfma_f32_16x16x32_bf16(Al00, Bh0, a, 0, 0, 0);
        a = __builtin_amdgcn_mfma_f32_16x16x32_bf16(Ah00, Bl0, a, 0, 0, 0);
        f32x4 b = __builtin_amdgcn_mfma_f32_16x16x32_bf16(Ah01, Bh1, zb, 0, 0, 0);
        b = __builtin_amdgcn_mfma_f32_16x16x32_bf16(Al01, Bh1, b, 0, 0, 0);
        b = __builtin_amdgcn_mfma_f32_16x16x32_bf16(Ah01, Bl1, b, 0, 0, 0);
        f32x4 dot0 = a + b;
        // row-tile 1
        f32x4 a1 = __builtin_amdgcn_mfma_f32_16x16x32_bf16(Ah10, Bh0, za, 0, 0, 0);
        a1 = __builtin_amdgcn_mfma_f32_16x16x32_bf16(Al10, Bh0, a1, 0, 0, 0);
        a1 = __builtin_amdgcn_mfma_f32_16x16x32_bf16(Ah10, Bl0, a1, 0, 0, 0);
        f32x4 b1 = __builtin_amdgcn_mfma_f32_16x16x32_bf16(Ah11, Bh1, zb, 0, 0, 0);
        b1 = __builtin_amdgcn_mfma_f32_16x16x32_bf16(Al11, Bh1, b1, 0, 0, 0);
        b1 = __builtin_amdgcn_mfma_f32_16x16x32_bf16(Ah11, Bl1, b1, 0, 0, 0);
        f32x4 dot1 = a1 + b1;

#pragma unroll
        for (int j = 0; j < 4; ++j) {
            float d2 = fmaf(dot0[j], -2.0f, srr0[j] + cnl);
            bool lt = d2 < m1_0[j];
            float mn2 = fminf(m2_0[j], d2);
            m2_0[j] = lt ? m1_0[j] : mn2;
            m1_0[j] = lt ? d2 : m1_0[j];
            ix0[j] = lt ? col : ix0[j];
        }
#pragma unroll
        for (int j = 0; j < 4; ++j) {
            float d2 = fmaf(dot1[j], -2.0f, srr1[j] + cnl);
            bool lt = d2 < m1_1[j];
            float mn2 = fminf(m2_1[j], d2);
            m2_1[j] = lt ? m1_1[j] : mn2;
            m1_1[j] = lt ? d2 : m1_1[j];
            ix1[j] = lt ? col : ix1[j];
        }
    }

    // cross-col reduce within 16-lane groups; u64 key = (bits(m1)<<32)|k
#pragma unroll
    for (int rt = 0; rt < 2; ++rt) {
#pragma unroll
        for (int j = 0; j < 4; ++j) {
            float m1v = rt ? m1_1[j] : m1_0[j];
            float m2v = rt ? m2_1[j] : m2_0[j];
            int   ixv = rt ? ix1[j] : ix0[j];
            u64 key = ((u64)__float_as_uint(m1v) << 32) | (unsigned)ixv;
#pragma unroll
            for (int off = 1; off < 16; off <<= 1) {
                u64 ko = __shfl_xor(key, off);
                float m2o = __shfl_xor(m2v, off);
                u64 kmax = key > ko ? key : ko;
                key = key < ko ? key : ko;
                m2v = fminf(fminf(m2v, m2o), __uint_as_float((unsigned)(kmax >> 32)));
            }
            if (lc == 0) {
                int n = n0 + rt * 16 + g * 4 + j;
                idxc[n] = (int)(unsigned)(key & 0xffffffffu);
                float gap = m2v - __uint_as_float((unsigned)(key >> 32));
                if (!(gap >= MARGIN)) {
                    int p = atomicAdd(flagcnt_c, 1);
                    if (p < N_PTS) flaglist[p] = n;
                }
            }
        }
    }
}

// ---------------- fixup: exact numpy-fp32 full-K rescan for flagged rows -----
__global__ __launch_bounds__(64) void fixup_kernel(
    const float* __restrict__ rem, const float* __restrict__ srr,
    const float* __restrict__ cbc, const float* __restrict__ cnc,
    int* __restrict__ idxc,
    const int* __restrict__ flagcnt_c, const int* __restrict__ flaglist)
{
#pragma clang fp contract(off)
    __shared__ float rlds[DIM];
    int lane = threadIdx.x;
    int cnt = *flagcnt_c; if (cnt > N_PTS) cnt = N_PTS;
    for (int i = blockIdx.x; i < cnt; i += gridDim.x) {
        int n = flaglist[i];
        rlds[lane] = rem[(size_t)n * DIM + lane];
        float srrv = srr[n];
        __syncthreads();
        u64 best = 0xffffffffffffffffull;
        for (int t = 0; t < KCB / 64; ++t) {
            int k = t * 64 + lane;
            const float* row = cbc + (size_t)k * DIM;
            float acc = 0.0f;
#pragma unroll
            for (int d = 0; d < DIM; ++d) acc = fmaf(rlds[d], row[d], acc);
            float t1 = 2.0f * acc;                  // exact
            float t2 = srrv - t1;                   // ref rounding order
            float dd = t2 + cnc[k];
            u64 key = ((u64)__float_as_uint(dd) << 32) | (unsigned)k;
            if (key < best) best = key;
        }
#pragma unroll
        for (int off = 1; off < 64; off <<= 1) {
            u64 o = __shfl_xor(best, off);
            if (o < best) best = o;
        }
        if (lane == 0) idxc[n] = (int)(unsigned)(best & 0xffffffffu);
        __syncthreads();
    }
}

// ---------------- epilogue: z_q (fp64; threshold ~2% of magnitude) -----------
__global__ __launch_bounds__(256) void zq_kernel(
    const float* __restrict__ z, const float* __restrict__ noise,
    const float* __restrict__ cbase, const int* __restrict__ idxA,
    float* __restrict__ out)
{
    int lane = threadIdx.x & 63;
    int n = blockIdx.x * 4 + (threadIdx.x >> 6);   // grid 16384
    size_t e = (size_t)n * DIM + lane;
    double zd = z[e];
    double rd = zd;
#pragma unroll
    for (int cc = 0; cc < NCB; ++cc) {
        int id = idxA[cc * N_PTS + n];
        rd -= (double)cbase[((size_t)cc * KCB + id) * DIM + lane];
    }
    double dir = -rd;                               // z_hard - z
    double rv = fma(1e-3, (double)noise[e], dir);
    double srv = rv * rv, sdir = dir * dir;
#pragma unroll
    for (int off = 32; off >= 1; off >>= 1) {
        srv  += __shfl_xor(srv, off);
        sdir += __shfl_xor(sdir, off);
    }
    double em = sqrt(sdir);
    double nn = sqrt(srv); nn = nn > 1e-12 ? nn : 1e-12;
    out[e] = (float)(zd + em * rv / nn);
}

// ---------------- histogram + idx output (as float32) ------------------------
__global__ __launch_bounds__(256) void hist_kernel(
    const int* __restrict__ idxA, float* __restrict__ out_idx, int* __restrict__ counts)
{
    int t = blockIdx.x * 256 + threadIdx.x;        // C*N, grid 1024
    int v = idxA[t];
    out_idx[t] = (float)v;
    atomicAdd(&counts[(t >> 16) * KCB + v], 1);
}

// ---------------- perplexity -------------------------------------------------
__global__ __launch_bounds__(1024) void perp_kernel(const int* __restrict__ counts,
                                                    float* __restrict__ out)
{
    __shared__ double red[16];
    int tid = threadIdx.x, lane = tid & 63, w = tid >> 6;
    for (int c = 0; c < NCB; ++c) {
        double p = (double)counts[c * KCB + tid] / (double)N_PTS;
        double v = p * log(p + 1e-10);
#pragma unroll
        for (int off = 32; off >= 1; off >>= 1) v += __shfl_xor(v, off);
        if (lane == 0) red[w] = v;
        __syncthreads();
        if (tid == 0) {
            double ssum = 0.0;
            for (int i = 0; i < 16; ++i) ssum += red[i];
            out[c] = (float)exp(-ssum);
        }
        __syncthreads();
    }
}

extern "C" void kernel_launch(void* const* d_in, const int* in_sizes, int n_in,
                              void* d_out, int out_size, void* d_ws, size_t ws_size,
                              hipStream_t stream)
{
    const float* z     = (const float*)d_in[0];
    const float* cbook = (const float*)d_in[1];   // [C,K,D]
    const float* noise = (const float*)d_in[2];
    float* out = (float*)d_out;
    char* ws = (char*)d_ws;

    // rem scratch = d_out's z_q region (16MB), overwritten by zq at the end.
    float* rem = out;

    // ws layout (~19.4 MB)
    unsigned short* remh = (unsigned short*)(ws);                // N*D bf16  8,388,608
    unsigned short* reml = (unsigned short*)(ws + 8388608);      // N*D bf16  8,388,608
    unsigned short* cbh  = (unsigned short*)(ws + 16777216);     // C*K*D       524,288
    unsigned short* cbl  = (unsigned short*)(ws + 17301504);     // C*K*D       524,288
    int*   idxA     = (int*)  (ws + 17825792);                   // C*N       1,048,576
    float* cnp      = (float*)(ws + 18874368);                   // C*K          16,384
    int*   counts   = (int*)  (ws + 18890752);                   // C*K          16,384
    float* srr      = (float*)(ws + 18907136);                   // N           262,144
    int*   flagcnt  = (int*)  (ws + 19169280);                   // 4 (+pad)        256
    int*   flaglist = (int*)  (ws + 19169536);                   // N           262,144

    prep_kernel<<<16, 256, 0, stream>>>(cbook, cnp, cbh, cbl, counts, flagcnt);

    for (int c = 0; c < NCB; ++c) {
        const float* cb_prev = (c == 0) ? nullptr : cbook + (size_t)(c - 1) * KCB * DIM;
        const int*   ix_prev = (c == 0) ? nullptr : idxA + (size_t)(c - 1) * N_PTS;
        const float* usrc    = (c == 0) ? z : rem;
        uprr_kernel<<<N_PTS / 4, 256, 0, stream>>>(
            usrc, cb_prev, ix_prev, rem, remh, reml, srr);
        dist_kernel<<<N_PTS / 128, 256, 0, stream>>>(
            remh, reml, cbh + (size_t)c * KCB * DIM, cbl + (size_t)c * KCB * DIM,
            cnp + c * KCB, srr, idxA + (size_t)c * N_PTS, flagcnt + c, flaglist);
        fixup_kernel<<<1024, 64, 0, stream>>>(
            rem, srr, cbook + (size_t)c * KCB * DIM, cnp + c * KCB,
            idxA + (size_t)c * N_PTS, flagcnt + c, flaglist);
    }

    zq_kernel<<<N_PTS / 4, 256, 0, stream>>>(z, noise, cbook, idxA, out);
    hist_kernel<<<NCB * N_PTS / 256, 256, 0, stream>>>(
        idxA, out + (size_t)N_PTS * DIM, counts);
    perp_kernel<<<1, 1024, 0, stream>>>(
        counts, out + (size_t)N_PTS * DIM + (size_t)NCB * N_PTS);
}